// Round 4
// baseline (119.299 us; speedup 1.0000x reference)
//
#include <hip/hip_runtime.h>
#include <math.h>

// Round 12: delete the Q materialization roundtrip.
//  - k_attn stages its own 64-pixel x tile (16.6KB LDS, overlays mrg region),
//    computes theta via the same MFMA path into a small LDS tile, and builds
//    Q B-frags locally. Aggregate theta MFMA work unchanged (relocated).
//  - k_qkv loses the theta branch + Q emit; QH/QL (16MB roundtrip) deleted.
//  - epilogue x-residual loads early-issued right after the KV loop (qh/ql
//    dead -> free VGPRs), latency hidden under the merge phase.

#define B_SZ 16
#define HW 4096
#define NKV 1024
#define XSTR 65
#define YS 40
#define LOG2E 1.4426950408889634f

typedef __attribute__((ext_vector_type(8))) short bfrag;
typedef __attribute__((ext_vector_type(4))) short sfrag;
typedef __attribute__((ext_vector_type(4))) float f32x4;

static __device__ __forceinline__ ushort f2bf(float v) {
  union { float f; uint u; } c; c.f = v;
  uint b = c.u + 0x7FFFu + ((c.u >> 16) & 1u);
  return (ushort)(b >> 16);
}
static __device__ __forceinline__ float bf2f(ushort h) {
  union { uint u; float f; } c; c.u = (uint)h << 16; return c.f;
}
// packed RNE f32x2 -> bf16x2 (lo16=bf(a), hi16=bf(b))
static __device__ __forceinline__ uint cvtpk(float a, float b) {
  uint r; asm("v_cvt_pk_bf16_f32 %0, %1, %2" : "=v"(r) : "v"(a), "v"(b));
  return r;
}
// hi/lo split of a pair: h = packed hi bf16s, l = packed residual bf16s
static __device__ __forceinline__ void split2(float a, float b, uint& h, uint& l) {
  h = cvtpk(a, b);
  float ha = __uint_as_float(h << 16);
  float hb = __uint_as_float(h & 0xFFFF0000u);
  l = cvtpk(a - ha, b - hb);
}

// ---------------- kernel 0: weight frag planes (runs once, 1 block) ----------------
__global__ __launch_bounds__(256) void k_prep(
    const float* __restrict__ wt, const float* __restrict__ wp,
    const float* __restrict__ wo, const float* __restrict__ wW,
    ushort* __restrict__ WTH, ushort* __restrict__ WTL,
    ushort* __restrict__ WPH, ushort* __restrict__ WPL,
    ushort* __restrict__ WOH, ushort* __restrict__ WWH,
    ushort* __restrict__ WWL) {
  int t = threadIdx.x;
  int p = t >> 6, lane = t & 63, l15 = lane & 15, quad = lane >> 4;
  {
    int nt = p >> 1, kh2 = p & 1;
    const float* rt = wt + (size_t)(nt * 16 + l15) * 64 + kh2 * 32 + quad * 8;
    const float* rp = wp + (size_t)(nt * 16 + l15) * 64 + kh2 * 32 + quad * 8;
    const float* ro = wo + (size_t)(nt * 16 + l15) * 64 + kh2 * 32 + quad * 8;
    union { ushort u[8]; uint4 v; } th, tl, ph, pl, oh;
    #pragma unroll
    for (int j = 0; j < 8; ++j) {
      float v = rt[j] * LOG2E;
      ushort hb = f2bf(v);
      th.u[j] = hb; tl.u[j] = f2bf(v - bf2f(hb));
      v = rp[j]; hb = f2bf(v);
      ph.u[j] = hb; pl.u[j] = f2bf(v - bf2f(hb));
      oh.u[j] = f2bf(ro[j]);
    }
    size_t base = (size_t)t * 8;            // (p*64+lane)*8
    *(uint4*)(WTH + base) = th.v;
    *(uint4*)(WTL + base) = tl.v;
    *(uint4*)(WPH + base) = ph.v;
    *(uint4*)(WPL + base) = pl.v;
    *(uint4*)(WOH + base) = oh.v;
  }
  #pragma unroll
  for (int s = 0; s < 2; ++s) {
    int idx = s * 256 + t;
    int p2 = idx >> 6, ln = idx & 63;
    int fl = ln & 15, fq = ln >> 4;
    int wv = p2 >> 1, kt = p2 & 1;
    const float* rw = wW + (size_t)(wv * 16 + fl) * 32 + kt * 16 + fq * 4;
    union { ushort u[4]; uint2 v; } h, l;
    #pragma unroll
    for (int j = 0; j < 4; ++j) {
      float v = rw[j];
      ushort hb = f2bf(v);
      h.u[j] = hb; l.u[j] = f2bf(v - bf2f(hb));
    }
    *(uint2*)(WWH + (size_t)idx * 4) = h.v;
    *(uint2*)(WWL + (size_t)idx * 4) = l.v;
  }
}

// ---------------- kernel 1: K/V via MFMA -> swizzled frag planes ----------------
// 512 thr = 8 waves; block = 128 pixels = 2 image rows; grid = 16*32.
__global__ __launch_bounds__(512) void k_qkv(
    const float* __restrict__ x,
    const ushort* __restrict__ WPH, const ushort* __restrict__ WPL,
    const float* __restrict__ bp,
    const ushort* __restrict__ WOH, const float* __restrict__ bo,
    ushort* __restrict__ KH, ushort* __restrict__ KL, ushort* __restrict__ VF) {
  __shared__ float sx[128 * XSTR];              // 33280 B  [pix][ch]
  __shared__ float sPool[2][2][32][33];         // 16896 B

  int t = threadIdx.x;
  int W = t >> 6, lane = t & 63, l15 = lane & 15, quad = lane >> 4;
  int bb = blockIdx.x >> 5, rg = blockIdx.x & 31;
  int p0 = rg * 128;

  // coalesced x load + transpose to [pix][ch]
  #pragma unroll
  for (int i = 0; i < 4; ++i) {
    int f = i * 512 + t;
    int c = f >> 5, u = f & 31;
    float4 v = *(const float4*)(x + ((size_t)bb << 18) + (size_t)c * HW + p0 + 4 * u);
    sx[(4*u+0) * XSTR + c] = v.x;
    sx[(4*u+1) * XSTR + c] = v.y;
    sx[(4*u+2) * XSTR + c] = v.z;
    sx[(4*u+3) * XSTR + c] = v.w;
  }
  __syncthreads();

  // x A-frags (hi/lo, 2 k-halves) from LDS (b32, conflict-free) via cvt_pk
  int pix = W * 16 + l15;
  bfrag xh[2], xl[2];
  #pragma unroll
  for (int kh2 = 0; kh2 < 2; ++kh2) {
    union { uint u[4]; bfrag f; } H, L;
    #pragma unroll
    for (int jj = 0; jj < 4; ++jj) {
      float v0 = sx[pix * XSTR + kh2 * 32 + quad * 8 + 2 * jj];
      float v1 = sx[pix * XSTR + kh2 * 32 + quad * 8 + 2 * jj + 1];
      split2(v0, v1, H.u[jj], L.u[jj]);
    }
    xh[kh2] = H.f;
    xl[kh2] = L.f;
  }

  int prow = (W * 16 + quad * 4) >> 6;
  int px2  = ((W * 16 + quad * 4) & 63) >> 1;

  f32x4 acc[2];

  // PHI, 3-term -> horizontal-pair max into sPool[0]
  acc[0] = (f32x4){0.f,0.f,0.f,0.f}; acc[1] = (f32x4){0.f,0.f,0.f,0.f};
  #pragma unroll
  for (int kh2 = 0; kh2 < 2; ++kh2)
    #pragma unroll
    for (int nt = 0; nt < 2; ++nt) {
      bfrag wh = *(const bfrag*)(WPH + ((size_t)(nt * 2 + kh2) * 64 + lane) * 8);
      bfrag wl = *(const bfrag*)(WPL + ((size_t)(nt * 2 + kh2) * 64 + lane) * 8);
      acc[nt] = __builtin_amdgcn_mfma_f32_16x16x32_bf16(xh[kh2], wh, acc[nt], 0, 0, 0);
      acc[nt] = __builtin_amdgcn_mfma_f32_16x16x32_bf16(xl[kh2], wh, acc[nt], 0, 0, 0);
      acc[nt] = __builtin_amdgcn_mfma_f32_16x16x32_bf16(xh[kh2], wl, acc[nt], 0, 0, 0);
    }
  #pragma unroll
  for (int nt = 0; nt < 2; ++nt) {
    float bias = bp[nt * 16 + l15];
    sPool[0][prow][px2    ][nt * 16 + l15] = fmaxf(acc[nt][0], acc[nt][1]) + bias;
    sPool[0][prow][px2 + 1][nt * 16 + l15] = fmaxf(acc[nt][2], acc[nt][3]) + bias;
  }

  // ORIGIN (V), 2-term -> sPool[1]
  acc[0] = (f32x4){0.f,0.f,0.f,0.f}; acc[1] = (f32x4){0.f,0.f,0.f,0.f};
  #pragma unroll
  for (int kh2 = 0; kh2 < 2; ++kh2)
    #pragma unroll
    for (int nt = 0; nt < 2; ++nt) {
      bfrag wh = *(const bfrag*)(WOH + ((size_t)(nt * 2 + kh2) * 64 + lane) * 8);
      acc[nt] = __builtin_amdgcn_mfma_f32_16x16x32_bf16(xh[kh2], wh, acc[nt], 0, 0, 0);
      acc[nt] = __builtin_amdgcn_mfma_f32_16x16x32_bf16(xl[kh2], wh, acc[nt], 0, 0, 0);
    }
  #pragma unroll
  for (int nt = 0; nt < 2; ++nt) {
    float bias = bo[nt * 16 + l15];
    sPool[1][prow][px2    ][nt * 16 + l15] = fmaxf(acc[nt][0], acc[nt][1]) + bias;
    sPool[1][prow][px2 + 1][nt * 16 + l15] = fmaxf(acc[nt][2], acc[nt][3]) + bias;
  }
  __syncthreads();

  // ---- emit K frags
  #pragma unroll
  for (int f = t; f < 1024; f += 512) {
    int tt = f >> 9, rem = f & 511;
    int ln = rem >> 3, j = rem & 7;
    int kvl = tt * 16 + (ln & 15);
    int ch = (ln >> 4) * 8 + j;
    float v = fmaxf(sPool[0][0][kvl][ch], sPool[0][1][kvl][ch]);
    ushort hb = f2bf(v);
    size_t base = ((size_t)(bb * 64 + rg * 2 + tt) * 64 + ln) * 8 + j;
    KH[base] = hb;
    KL[base] = f2bf(v - bf2f(hb));
  }

  // ---- emit V frags
  #pragma unroll
  for (int f = t; f < 1024; f += 512) {
    int tt = f >> 9, mt = (f >> 8) & 1;
    int ln = (f >> 2) & 63, j = f & 3;
    int kvl = tt * 16 + ((ln >> 4) << 2) + j;
    int ch = mt * 16 + (ln & 15);
    float v = fmaxf(sPool[1][0][kvl][ch], sPool[1][1][kvl][ch]);
    VF[(((size_t)(bb * 64 + rg * 2 + tt) * 2 + mt) * 64 + ln) * 4 + j] = f2bf(v);
  }
}

// ---------------- kernel 2: fused theta + register-chained flash attention ----------------
// 256 thr = 4 waves; block = 64 q (4 tiles); wave w owns kv [w*256, w*256+256).
// Stages its own x tile, computes theta locally (no Q roundtrip).
__global__ __launch_bounds__(256, 4) void k_attn(
    const ushort* __restrict__ KH, const ushort* __restrict__ KL,
    const ushort* __restrict__ VF,
    const ushort* __restrict__ WTH, const ushort* __restrict__ WTL,
    const float* __restrict__ bt,
    const float* __restrict__ x,
    const ushort* __restrict__ WWH, const ushort* __restrict__ WWL,
    const float* __restrict__ bW, float* __restrict__ z) {
  __shared__ float smem[4 * 64 * 36 + 4 * 64];   // 37888 B
  float* mrg = smem;                              // [w][q 64][ch 36] (after loop)
  float* sS  = smem + 4 * 64 * 36;                // [w][q 64]
  float* sxa = smem;                              // [64][65] x-stage (overlays mrg)
  float* sth = smem + 64 * 65;                    // [64][33] theta tile

  int t = threadIdx.x;
  int w = t >> 6, lane = t & 63, l15 = lane & 15, quad = lane >> 4;
  int bb = blockIdx.x >> 6;
  int bq = blockIdx.x & 63;                       // block q-tile group (4 tiles)
  int p0 = bq * 64;

  // ---- stage x[ch][p0..p0+64) -> sxa[pix][ch]
  #pragma unroll
  for (int i = 0; i < 4; ++i) {
    int f = i * 256 + t;
    int c = f >> 4, u = (f & 15) * 4;
    float4 v = *(const float4*)(x + ((size_t)bb << 18) + (size_t)c * HW + p0 + u);
    sxa[(u+0) * 65 + c] = v.x;
    sxa[(u+1) * 65 + c] = v.y;
    sxa[(u+2) * 65 + c] = v.z;
    sxa[(u+3) * 65 + c] = v.w;
  }
  __syncthreads();

  // ---- x A-frags for this wave's 16 pixels
  int pix = w * 16 + l15;
  bfrag xh[2], xl[2];
  #pragma unroll
  for (int kh2 = 0; kh2 < 2; ++kh2) {
    union { uint u[4]; bfrag f; } H, L;
    #pragma unroll
    for (int jj = 0; jj < 4; ++jj) {
      float v0 = sxa[pix * 65 + kh2 * 32 + quad * 8 + 2 * jj];
      float v1 = sxa[pix * 65 + kh2 * 32 + quad * 8 + 2 * jj + 1];
      split2(v0, v1, H.u[jj], L.u[jj]);
    }
    xh[kh2] = H.f;
    xl[kh2] = L.f;
  }

  // ---- theta (x LOG2E), 3-term -> sth[pix][cout]
  {
    f32x4 acc[2];
    acc[0] = (f32x4){0.f,0.f,0.f,0.f}; acc[1] = (f32x4){0.f,0.f,0.f,0.f};
    #pragma unroll
    for (int kh2 = 0; kh2 < 2; ++kh2)
      #pragma unroll
      for (int nt = 0; nt < 2; ++nt) {
        bfrag wh = *(const bfrag*)(WTH + ((size_t)(nt * 2 + kh2) * 64 + lane) * 8);
        bfrag wl = *(const bfrag*)(WTL + ((size_t)(nt * 2 + kh2) * 64 + lane) * 8);
        acc[nt] = __builtin_amdgcn_mfma_f32_16x16x32_bf16(xh[kh2], wh, acc[nt], 0, 0, 0);
        acc[nt] = __builtin_amdgcn_mfma_f32_16x16x32_bf16(xl[kh2], wh, acc[nt], 0, 0, 0);
        acc[nt] = __builtin_amdgcn_mfma_f32_16x16x32_bf16(xh[kh2], wl, acc[nt], 0, 0, 0);
      }
    #pragma unroll
    for (int nt = 0; nt < 2; ++nt) {
      float bias = bt[nt * 16 + l15] * LOG2E;
      #pragma unroll
      for (int r = 0; r < 4; ++r)
        sth[(w * 16 + quad * 4 + r) * 33 + nt * 16 + l15] = acc[nt][r] + bias;
    }
  }
  __syncthreads();

  // ---- Q B-frags for all 4 q-tiles (hi/lo)
  bfrag qh[4], ql[4];
  #pragma unroll
  for (int qt = 0; qt < 4; ++qt) {
    union { uint u[4]; bfrag f; } H, L;
    #pragma unroll
    for (int jj = 0; jj < 4; ++jj) {
      float v0 = sth[(qt * 16 + l15) * 33 + quad * 8 + 2 * jj];
      float v1 = sth[(qt * 16 + l15) * 33 + quad * 8 + 2 * jj + 1];
      split2(v0, v1, H.u[jj], L.u[jj]);
    }
    qh[qt] = H.f;
    ql[qt] = L.f;
  }
  __syncthreads();   // all waves done reading sth/sxa before mrg writes

  const ushort* KHb = KH + (size_t)bb * 64 * 64 * 8;
  const ushort* KLb = KL + (size_t)bb * 64 * 64 * 8;
  const ushort* VFb = VF + (size_t)bb * 64 * 2 * 64 * 4;

  f32x4 accO[4][2];
  float spart[4] = {0.f, 0.f, 0.f, 0.f};
  #pragma unroll
  for (int qt = 0; qt < 4; ++qt) {
    accO[qt][0] = (f32x4){0.f,0.f,0.f,0.f};
    accO[qt][1] = (f32x4){0.f,0.f,0.f,0.f};
  }

  bfrag kh[2], kl[2];
  sfrag vf[2][2];
  auto loadT = [&](int buf, int i) {
    int gt = w * 16 + i;
    size_t kb = ((size_t)gt * 64 + lane) * 8;
    kh[buf] = *(const bfrag*)(KHb + kb);
    kl[buf] = *(const bfrag*)(KLb + kb);
    vf[buf][0] = *(const sfrag*)(VFb + (((size_t)gt * 2 + 0) * 64 + lane) * 4);
    vf[buf][1] = *(const sfrag*)(VFb + (((size_t)gt * 2 + 1) * 64 + lane) * 4);
  };

  loadT(0, 0);
  #pragma unroll 2
  for (int i = 0; i < 16; ++i) {
    int cur = i & 1;
    if (i < 15) loadT(cur ^ 1, i + 1);
    __builtin_amdgcn_s_setprio(1);
    #pragma unroll
    for (int qt = 0; qt < 4; ++qt) {
      f32x4 s = (f32x4){0.f,0.f,0.f,0.f};
      s = __builtin_amdgcn_mfma_f32_16x16x32_bf16(kh[cur], qh[qt], s, 0, 0, 0);
      s = __builtin_amdgcn_mfma_f32_16x16x32_bf16(kh[cur], ql[qt], s, 0, 0, 0);
      s = __builtin_amdgcn_mfma_f32_16x16x32_bf16(kl[cur], qh[qt], s, 0, 0, 0);
      float e0 = exp2f(s[0]), e1 = exp2f(s[1]);
      float e2 = exp2f(s[2]), e3 = exp2f(s[3]);
      spart[qt] += (e0 + e1) + (e2 + e3);
      union { uint2 u; sfrag s4; } pk;   // truncation: normalization cancels bias
      pk.u.x = (__float_as_uint(e0) >> 16) | (__float_as_uint(e1) & 0xFFFF0000u);
      pk.u.y = (__float_as_uint(e2) >> 16) | (__float_as_uint(e3) & 0xFFFF0000u);
      // P^T C-layout == B-frag of K=16 MFMA; A = V^T  ->  O^T += V^T . P^T
      accO[qt][0] = __builtin_amdgcn_mfma_f32_16x16x16bf16_1k(vf[cur][0], pk.s4, accO[qt][0], 0, 0, 0);
      accO[qt][1] = __builtin_amdgcn_mfma_f32_16x16x16bf16_1k(vf[cur][1], pk.s4, accO[qt][1], 0, 0, 0);
    }
    __builtin_amdgcn_s_setprio(0);
  }

  // early-issue the epilogue x-residual loads (latency hidden under merge)
  float xres[4][4];
  #pragma unroll
  for (int nt = 0; nt < 4; ++nt)
    #pragma unroll
    for (int r = 0; r < 4; ++r) {
      int cout = w * 16 + quad * 4 + r;
      xres[nt][r] = x[((size_t)bb << 18) + ((size_t)cout << 12)
                    + (size_t)(bq * 4 + nt) * 16 + l15];
    }

  // wave-level kv-sum: reduce spart across the 4 quads (lanes xor 16/32)
  #pragma unroll
  for (int qt = 0; qt < 4; ++qt) {
    spart[qt] += __shfl_xor(spart[qt], 16);
    spart[qt] += __shfl_xor(spart[qt], 32);
  }

  // merge partials across waves
  #pragma unroll
  for (int qt = 0; qt < 4; ++qt) {
    #pragma unroll
    for (int mt = 0; mt < 2; ++mt)
      *(float4*)&mrg[((size_t)w * 64 + qt * 16 + l15) * 36 + mt * 16 + quad * 4] =
          make_float4(accO[qt][mt][0], accO[qt][mt][1], accO[qt][mt][2], accO[qt][mt][3]);
    if (lane < 16) sS[w * 64 + qt * 16 + l15] = spart[qt];
  }
  __syncthreads();

  // reduce over waves + normalize (thread -> q = t>>2, 8 channels)
  int rq = t >> 2, rc = (t & 3) * 8;
  float yv[8];
  {
    float ssum = sS[rq] + sS[64 + rq] + sS[128 + rq] + sS[192 + rq];
    float inv = 1.0f / ssum;
    #pragma unroll
    for (int h = 0; h < 2; ++h) {
      float4 a = *(const float4*)&mrg[(size_t)rq * 36 + rc + 4 * h];
      float4 b = *(const float4*)&mrg[(size_t)(64 + rq) * 36 + rc + 4 * h];
      float4 c = *(const float4*)&mrg[(size_t)(128 + rq) * 36 + rc + 4 * h];
      float4 d = *(const float4*)&mrg[(size_t)(192 + rq) * 36 + rc + 4 * h];
      yv[4*h+0] = (a.x + b.x + c.x + d.x) * inv;
      yv[4*h+1] = (a.y + b.y + c.y + d.y) * inv;
      yv[4*h+2] = (a.z + b.z + c.z + d.z) * inv;
      yv[4*h+3] = (a.w + b.w + c.w + d.w) * inv;
    }
  }
  __syncthreads();

  // write y bf16 hi/lo planes into reused mrg space (cvt_pk pairs)
  ushort* yH = (ushort*)mrg;                 // [q][YS]
  ushort* yL = yH + 64 * YS;
  {
    union { uint u[4]; uint4 v; } Hh, Ll;
    #pragma unroll
    for (int jj = 0; jj < 4; ++jj)
      split2(yv[2 * jj], yv[2 * jj + 1], Hh.u[jj], Ll.u[jj]);
    *(uint4*)&yH[rq * YS + rc] = Hh.v;
    *(uint4*)&yL[rq * YS + rc] = Ll.v;
  }
  __syncthreads();

  // epilogue: wave w -> cout tile [w*16, w*16+16); z = W.y + bW + x
  sfrag ah[2], al[2];
  #pragma unroll
  for (int kt = 0; kt < 2; ++kt) {
    ah[kt] = *(const sfrag*)(WWH + ((size_t)(w * 2 + kt) * 64 + lane) * 4);
    al[kt] = *(const sfrag*)(WWL + ((size_t)(w * 2 + kt) * 64 + lane) * 4);
  }
  #pragma unroll
  for (int nt = 0; nt < 4; ++nt) {
    f32x4 d = (f32x4){0.f,0.f,0.f,0.f};
    #pragma unroll
    for (int kt = 0; kt < 2; ++kt) {
      sfrag yhf = *(const sfrag*)&yH[(nt * 16 + l15) * YS + kt * 16 + quad * 4];
      sfrag ylf = *(const sfrag*)&yL[(nt * 16 + l15) * YS + kt * 16 + quad * 4];
      d = __builtin_amdgcn_mfma_f32_16x16x16bf16_1k(ah[kt], yhf, d, 0, 0, 0);
      d = __builtin_amdgcn_mfma_f32_16x16x16bf16_1k(al[kt], yhf, d, 0, 0, 0);
      d = __builtin_amdgcn_mfma_f32_16x16x16bf16_1k(ah[kt], ylf, d, 0, 0, 0);
    }
    #pragma unroll
    for (int r = 0; r < 4; ++r) {
      int cout = w * 16 + quad * 4 + r;
      size_t zi = ((size_t)bb << 18) + ((size_t)cout << 12)
                + (size_t)(bq * 4 + nt) * 16 + l15;
      z[zi] = d[r] + bW[cout] + xres[nt][r];
    }
  }
}

extern "C" void kernel_launch(void* const* d_in, const int* in_sizes, int n_in,
                              void* d_out, int out_size, void* d_ws, size_t ws_size,
                              hipStream_t stream) {
  const float* x   = (const float*)d_in[0];
  const float* w_o = (const float*)d_in[1];
  const float* b_o = (const float*)d_in[2];
  const float* w_t = (const float*)d_in[3];
  const float* b_t = (const float*)d_in[4];
  const float* w_p = (const float*)d_in[5];
  const float* b_p = (const float*)d_in[6];
  const float* w_W = (const float*)d_in[7];
  const float* b_W = (const float*)d_in[8];
  float* z = (float*)d_out;

  ushort* KH = (ushort*)d_ws;                         // 16*64*64*8 = 524288
  ushort* KL = KH + 524288;
  ushort* VF = KL + 524288;                           // 16*64*2*64*4 = 524288
  ushort* WTH = VF + 524288;                          // 4*64*8 = 2048 each
  ushort* WTL = WTH + 2048;
  ushort* WPH = WTL + 2048;
  ushort* WPL = WPH + 2048;
  ushort* WOH = WPL + 2048;
  ushort* WWH = WOH + 2048;                           // 8*64*4 = 2048 each
  ushort* WWL = WWH + 2048;

  k_prep<<<dim3(1), dim3(256), 0, stream>>>(
      w_t, w_p, w_o, w_W, WTH, WTL, WPH, WPL, WOH, WWH, WWL);
  k_qkv<<<dim3(B_SZ * 32), dim3(512), 0, stream>>>(
      x, WPH, WPL, b_p, WOH, b_o, KH, KL, VF);
  k_attn<<<dim3(B_SZ * 64), dim3(256), 0, stream>>>(
      KH, KL, VF, WTH, WTL, b_t, x, WWH, WWL, b_W, z);
}

// Round 6
// 117.319 us; speedup vs baseline: 1.0169x; 1.0169x over previous
//
#include <hip/hip_runtime.h>
#include <math.h>

// Round 14: exact R11 (banked best, 117.8) + vectorized K/V emit in k_qkv.
//  - R13 (wave-per-q-tile) abandoned: NaN, and concept was wrong anyway
//    (4x KV L2 traffic, ~786MB vs 197MB). R11's 64q/block KV reuse is best.
//  - K emit: one pass, j-pairs via split2 (cvt_pk), uint stores (was 2048
//    scalar 2B stores in 2 passes). V emit: j-pairs via cvtpk, uint stores.
//    RNE identical to f2bf -> bit-identical output.

#define B_SZ 16
#define HW 4096
#define NKV 1024
#define XSTR 65
#define YS 40
#define LOG2E 1.4426950408889634f

typedef __attribute__((ext_vector_type(8))) short bfrag;
typedef __attribute__((ext_vector_type(4))) short sfrag;
typedef __attribute__((ext_vector_type(4))) float f32x4;

static __device__ __forceinline__ ushort f2bf(float v) {
  union { float f; uint u; } c; c.f = v;
  uint b = c.u + 0x7FFFu + ((c.u >> 16) & 1u);
  return (ushort)(b >> 16);
}
static __device__ __forceinline__ float bf2f(ushort h) {
  union { uint u; float f; } c; c.u = (uint)h << 16; return c.f;
}
// packed RNE f32x2 -> bf16x2 (lo16=bf(a), hi16=bf(b))
static __device__ __forceinline__ uint cvtpk(float a, float b) {
  uint r; asm("v_cvt_pk_bf16_f32 %0, %1, %2" : "=v"(r) : "v"(a), "v"(b));
  return r;
}
// hi/lo split of a pair: h = packed hi bf16s, l = packed residual bf16s
static __device__ __forceinline__ void split2(float a, float b, uint& h, uint& l) {
  h = cvtpk(a, b);
  float ha = __uint_as_float(h << 16);
  float hb = __uint_as_float(h & 0xFFFF0000u);
  l = cvtpk(a - ha, b - hb);
}

// ---------------- kernel 0: weight frag planes (runs once, 1 block) ----------------
__global__ __launch_bounds__(256) void k_prep(
    const float* __restrict__ wt, const float* __restrict__ wp,
    const float* __restrict__ wo, const float* __restrict__ wW,
    ushort* __restrict__ WTH, ushort* __restrict__ WTL,
    ushort* __restrict__ WPH, ushort* __restrict__ WPL,
    ushort* __restrict__ WOH, ushort* __restrict__ WWH,
    ushort* __restrict__ WWL) {
  int t = threadIdx.x;
  int p = t >> 6, lane = t & 63, l15 = lane & 15, quad = lane >> 4;
  {
    int nt = p >> 1, kh2 = p & 1;
    const float* rt = wt + (size_t)(nt * 16 + l15) * 64 + kh2 * 32 + quad * 8;
    const float* rp = wp + (size_t)(nt * 16 + l15) * 64 + kh2 * 32 + quad * 8;
    const float* ro = wo + (size_t)(nt * 16 + l15) * 64 + kh2 * 32 + quad * 8;
    union { ushort u[8]; uint4 v; } th, tl, ph, pl, oh;
    #pragma unroll
    for (int j = 0; j < 8; ++j) {
      float v = rt[j] * LOG2E;
      ushort hb = f2bf(v);
      th.u[j] = hb; tl.u[j] = f2bf(v - bf2f(hb));
      v = rp[j]; hb = f2bf(v);
      ph.u[j] = hb; pl.u[j] = f2bf(v - bf2f(hb));
      oh.u[j] = f2bf(ro[j]);
    }
    size_t base = (size_t)t * 8;            // (p*64+lane)*8
    *(uint4*)(WTH + base) = th.v;
    *(uint4*)(WTL + base) = tl.v;
    *(uint4*)(WPH + base) = ph.v;
    *(uint4*)(WPL + base) = pl.v;
    *(uint4*)(WOH + base) = oh.v;
  }
  #pragma unroll
  for (int s = 0; s < 2; ++s) {
    int idx = s * 256 + t;
    int p2 = idx >> 6, ln = idx & 63;
    int fl = ln & 15, fq = ln >> 4;
    int wv = p2 >> 1, kt = p2 & 1;
    const float* rw = wW + (size_t)(wv * 16 + fl) * 32 + kt * 16 + fq * 4;
    union { ushort u[4]; uint2 v; } h, l;
    #pragma unroll
    for (int j = 0; j < 4; ++j) {
      float v = rw[j];
      ushort hb = f2bf(v);
      h.u[j] = hb; l.u[j] = f2bf(v - bf2f(hb));
    }
    *(uint2*)(WWH + (size_t)idx * 4) = h.v;
    *(uint2*)(WWL + (size_t)idx * 4) = l.v;
  }
}

// ---------------- kernel 1: Q/K/V via MFMA -> swizzled frag planes ----------------
// 512 thr = 8 waves; block = 128 pixels = 2 image rows; grid = 16*32.
__global__ __launch_bounds__(512) void k_qkv(
    const float* __restrict__ x,
    const ushort* __restrict__ WTH, const ushort* __restrict__ WTL,
    const float* __restrict__ bt,
    const ushort* __restrict__ WPH, const ushort* __restrict__ WPL,
    const float* __restrict__ bp,
    const ushort* __restrict__ WOH, const float* __restrict__ bo,
    ushort* __restrict__ QH, ushort* __restrict__ QL,
    ushort* __restrict__ KH, ushort* __restrict__ KL, ushort* __restrict__ VF) {
  __shared__ float sx[128 * XSTR];              // 33280 B  [pix][ch] (reused for theta)
  __shared__ float sPool[2][2][32][33];         // 16896 B

  int t = threadIdx.x;
  int W = t >> 6, lane = t & 63, l15 = lane & 15, quad = lane >> 4;
  int bb = blockIdx.x >> 5, rg = blockIdx.x & 31;
  int p0 = rg * 128;

  // coalesced x load + transpose to [pix][ch]
  #pragma unroll
  for (int i = 0; i < 4; ++i) {
    int f = i * 512 + t;
    int c = f >> 5, u = f & 31;
    float4 v = *(const float4*)(x + ((size_t)bb << 18) + (size_t)c * HW + p0 + 4 * u);
    sx[(4*u+0) * XSTR + c] = v.x;
    sx[(4*u+1) * XSTR + c] = v.y;
    sx[(4*u+2) * XSTR + c] = v.z;
    sx[(4*u+3) * XSTR + c] = v.w;
  }
  __syncthreads();

  // x A-frags (hi/lo, 2 k-halves) from LDS (b32, conflict-free) via cvt_pk
  int pix = W * 16 + l15;
  bfrag xh[2], xl[2];
  #pragma unroll
  for (int kh2 = 0; kh2 < 2; ++kh2) {
    union { uint u[4]; bfrag f; } H, L;
    #pragma unroll
    for (int jj = 0; jj < 4; ++jj) {
      float v0 = sx[pix * XSTR + kh2 * 32 + quad * 8 + 2 * jj];
      float v1 = sx[pix * XSTR + kh2 * 32 + quad * 8 + 2 * jj + 1];
      split2(v0, v1, H.u[jj], L.u[jj]);
    }
    xh[kh2] = H.f;
    xl[kh2] = L.f;
  }
  __syncthreads();   // frags in regs; sx region now writable

  f32x4 acc[2];

  // THETA (x LOG2E), 3-term -> fp32 back into sx[pix][ch]
  acc[0] = (f32x4){0.f,0.f,0.f,0.f}; acc[1] = (f32x4){0.f,0.f,0.f,0.f};
  #pragma unroll
  for (int kh2 = 0; kh2 < 2; ++kh2)
    #pragma unroll
    for (int nt = 0; nt < 2; ++nt) {
      bfrag wh = *(const bfrag*)(WTH + ((size_t)(nt * 2 + kh2) * 64 + lane) * 8);
      bfrag wl = *(const bfrag*)(WTL + ((size_t)(nt * 2 + kh2) * 64 + lane) * 8);
      acc[nt] = __builtin_amdgcn_mfma_f32_16x16x32_bf16(xh[kh2], wh, acc[nt], 0, 0, 0);
      acc[nt] = __builtin_amdgcn_mfma_f32_16x16x32_bf16(xl[kh2], wh, acc[nt], 0, 0, 0);
      acc[nt] = __builtin_amdgcn_mfma_f32_16x16x32_bf16(xh[kh2], wl, acc[nt], 0, 0, 0);
    }
  #pragma unroll
  for (int nt = 0; nt < 2; ++nt) {
    float bias = bt[nt * 16 + l15] * LOG2E;
    #pragma unroll
    for (int r = 0; r < 4; ++r)
      sx[(W * 16 + quad * 4 + r) * XSTR + nt * 16 + l15] = acc[nt][r] + bias;
  }

  int prow = (W * 16 + quad * 4) >> 6;
  int px2  = ((W * 16 + quad * 4) & 63) >> 1;

  // PHI, 3-term -> horizontal-pair max into sPool[0]
  acc[0] = (f32x4){0.f,0.f,0.f,0.f}; acc[1] = (f32x4){0.f,0.f,0.f,0.f};
  #pragma unroll
  for (int kh2 = 0; kh2 < 2; ++kh2)
    #pragma unroll
    for (int nt = 0; nt < 2; ++nt) {
      bfrag wh = *(const bfrag*)(WPH + ((size_t)(nt * 2 + kh2) * 64 + lane) * 8);
      bfrag wl = *(const bfrag*)(WPL + ((size_t)(nt * 2 + kh2) * 64 + lane) * 8);
      acc[nt] = __builtin_amdgcn_mfma_f32_16x16x32_bf16(xh[kh2], wh, acc[nt], 0, 0, 0);
      acc[nt] = __builtin_amdgcn_mfma_f32_16x16x32_bf16(xl[kh2], wh, acc[nt], 0, 0, 0);
      acc[nt] = __builtin_amdgcn_mfma_f32_16x16x32_bf16(xh[kh2], wl, acc[nt], 0, 0, 0);
    }
  #pragma unroll
  for (int nt = 0; nt < 2; ++nt) {
    float bias = bp[nt * 16 + l15];
    sPool[0][prow][px2    ][nt * 16 + l15] = fmaxf(acc[nt][0], acc[nt][1]) + bias;
    sPool[0][prow][px2 + 1][nt * 16 + l15] = fmaxf(acc[nt][2], acc[nt][3]) + bias;
  }

  // ORIGIN (V), 2-term -> sPool[1]
  acc[0] = (f32x4){0.f,0.f,0.f,0.f}; acc[1] = (f32x4){0.f,0.f,0.f,0.f};
  #pragma unroll
  for (int kh2 = 0; kh2 < 2; ++kh2)
    #pragma unroll
    for (int nt = 0; nt < 2; ++nt) {
      bfrag wh = *(const bfrag*)(WOH + ((size_t)(nt * 2 + kh2) * 64 + lane) * 8);
      acc[nt] = __builtin_amdgcn_mfma_f32_16x16x32_bf16(xh[kh2], wh, acc[nt], 0, 0, 0);
      acc[nt] = __builtin_amdgcn_mfma_f32_16x16x32_bf16(xl[kh2], wh, acc[nt], 0, 0, 0);
    }
  #pragma unroll
  for (int nt = 0; nt < 2; ++nt) {
    float bias = bo[nt * 16 + l15];
    sPool[1][prow][px2    ][nt * 16 + l15] = fmaxf(acc[nt][0], acc[nt][1]) + bias;
    sPool[1][prow][px2 + 1][nt * 16 + l15] = fmaxf(acc[nt][2], acc[nt][3]) + bias;
  }
  __syncthreads();

  // ---- emit Q frags (cvt_pk pairs)
  {
    int qt = t >> 6, ln = t & 63, fl = ln & 15, fq = ln >> 4;
    union { uint u[4]; uint4 v; } Hh, Ll;
    #pragma unroll
    for (int jj = 0; jj < 4; ++jj) {
      float v0 = sx[(qt * 16 + fl) * XSTR + fq * 8 + 2 * jj];
      float v1 = sx[(qt * 16 + fl) * XSTR + fq * 8 + 2 * jj + 1];
      split2(v0, v1, Hh.u[jj], Ll.u[jj]);
    }
    size_t base = ((size_t)(bb * 256 + rg * 8 + qt) * 64 + ln) * 8;
    *(uint4*)(QH + base) = Hh.v;
    *(uint4*)(QL + base) = Ll.v;
  }

  // ---- emit K frags: j-pairs, packed hi/lo, uint stores (one pass)
  {
    int tt = t >> 8, ln = (t >> 2) & 63, jj = t & 3;
    int j0 = jj * 2;
    int fl = ln & 15, fq = ln >> 4;
    int kvl = tt * 16 + fl;
    float v0 = fmaxf(sPool[0][0][kvl][fq * 8 + j0    ], sPool[0][1][kvl][fq * 8 + j0    ]);
    float v1 = fmaxf(sPool[0][0][kvl][fq * 8 + j0 + 1], sPool[0][1][kvl][fq * 8 + j0 + 1]);
    uint h, l;
    split2(v0, v1, h, l);
    size_t base = ((size_t)(bb * 64 + rg * 2 + tt) * 64 + ln) * 8 + j0;
    *(uint*)(KH + base) = h;
    *(uint*)(KL + base) = l;
  }

  // ---- emit V frags: j-pairs, packed, uint stores (one pass)
  {
    int tt = t >> 8, mt = (t >> 7) & 1, ln = (t >> 1) & 63, jj = t & 1;
    int j0 = jj * 2;
    int fl = ln & 15, fq = ln >> 4;
    int kvl0 = tt * 16 + (fq << 2) + j0;
    int ch = mt * 16 + fl;
    float v0 = fmaxf(sPool[1][0][kvl0    ][ch], sPool[1][1][kvl0    ][ch]);
    float v1 = fmaxf(sPool[1][0][kvl0 + 1][ch], sPool[1][1][kvl0 + 1][ch]);
    uint h = cvtpk(v0, v1);
    size_t base = (((size_t)(bb * 64 + rg * 2 + tt) * 2 + mt) * 64 + ln) * 4 + j0;
    *(uint*)(VF + base) = h;
  }
}

// ---------------- kernel 2: register-chained flash attention ----------------
// 256 thr = 4 waves; block = 64 q (4 tiles); wave w owns kv [w*256, w*256+256).
__global__ __launch_bounds__(256, 4) void k_attn(
    const ushort* __restrict__ QH, const ushort* __restrict__ QL,
    const ushort* __restrict__ KH, const ushort* __restrict__ KL,
    const ushort* __restrict__ VF,
    const float* __restrict__ x,
    const ushort* __restrict__ WWH, const ushort* __restrict__ WWL,
    const float* __restrict__ bW, float* __restrict__ z) {
  __shared__ float smem[4 * 64 * 36 + 4 * 64];   // 37888 B: mrgO + sS (mrg reused for y)
  float* mrg = smem;                              // [w][q 64][ch 36]
  float* sS  = smem + 4 * 64 * 36;                // [w][q 64]

  int t = threadIdx.x;
  int w = t >> 6, lane = t & 63, l15 = lane & 15, quad = lane >> 4;
  int bb = blockIdx.x >> 6;
  int bq = blockIdx.x & 63;                       // block q-tile group (4 tiles)

  // Q frags for the block's 4 q-tiles (B[k=ch][n=q]), hi/lo
  bfrag qh[4], ql[4];
  #pragma unroll
  for (int qt = 0; qt < 4; ++qt) {
    size_t base = ((size_t)(bb * 256 + bq * 4 + qt) * 64 + lane) * 8;
    qh[qt] = *(const bfrag*)(QH + base);
    ql[qt] = *(const bfrag*)(QL + base);
  }

  const ushort* KHb = KH + (size_t)bb * 64 * 64 * 8;
  const ushort* KLb = KL + (size_t)bb * 64 * 64 * 8;
  const ushort* VFb = VF + (size_t)bb * 64 * 2 * 64 * 4;

  f32x4 accO[4][2];
  float spart[4] = {0.f, 0.f, 0.f, 0.f};
  #pragma unroll
  for (int qt = 0; qt < 4; ++qt) {
    accO[qt][0] = (f32x4){0.f,0.f,0.f,0.f};
    accO[qt][1] = (f32x4){0.f,0.f,0.f,0.f};
  }

  bfrag kh[2], kl[2];
  sfrag vf[2][2];
  auto loadT = [&](int buf, int i) {
    int gt = w * 16 + i;
    size_t kb = ((size_t)gt * 64 + lane) * 8;
    kh[buf] = *(const bfrag*)(KHb + kb);
    kl[buf] = *(const bfrag*)(KLb + kb);
    vf[buf][0] = *(const sfrag*)(VFb + (((size_t)gt * 2 + 0) * 64 + lane) * 4);
    vf[buf][1] = *(const sfrag*)(VFb + (((size_t)gt * 2 + 1) * 64 + lane) * 4);
  };

  loadT(0, 0);
  #pragma unroll 2
  for (int i = 0; i < 16; ++i) {
    int cur = i & 1;
    if (i < 15) loadT(cur ^ 1, i + 1);
    __builtin_amdgcn_s_setprio(1);
    #pragma unroll
    for (int qt = 0; qt < 4; ++qt) {
      f32x4 s = (f32x4){0.f,0.f,0.f,0.f};
      s = __builtin_amdgcn_mfma_f32_16x16x32_bf16(kh[cur], qh[qt], s, 0, 0, 0);
      s = __builtin_amdgcn_mfma_f32_16x16x32_bf16(kh[cur], ql[qt], s, 0, 0, 0);
      s = __builtin_amdgcn_mfma_f32_16x16x32_bf16(kl[cur], qh[qt], s, 0, 0, 0);
      float e0 = exp2f(s[0]), e1 = exp2f(s[1]);
      float e2 = exp2f(s[2]), e3 = exp2f(s[3]);
      spart[qt] += (e0 + e1) + (e2 + e3);
      union { uint2 u; sfrag s4; } pk;   // truncation: normalization cancels bias
      pk.u.x = (__float_as_uint(e0) >> 16) | (__float_as_uint(e1) & 0xFFFF0000u);
      pk.u.y = (__float_as_uint(e2) >> 16) | (__float_as_uint(e3) & 0xFFFF0000u);
      // P^T C-layout == B-frag of K=16 MFMA; A = V^T  ->  O^T += V^T . P^T
      accO[qt][0] = __builtin_amdgcn_mfma_f32_16x16x16bf16_1k(vf[cur][0], pk.s4, accO[qt][0], 0, 0, 0);
      accO[qt][1] = __builtin_amdgcn_mfma_f32_16x16x16bf16_1k(vf[cur][1], pk.s4, accO[qt][1], 0, 0, 0);
    }
    __builtin_amdgcn_s_setprio(0);
  }

  // wave-level kv-sum: reduce spart across the 4 quads (lanes xor 16/32)
  #pragma unroll
  for (int qt = 0; qt < 4; ++qt) {
    spart[qt] += __shfl_xor(spart[qt], 16);
    spart[qt] += __shfl_xor(spart[qt], 32);
  }

  // merge partials across waves
  #pragma unroll
  for (int qt = 0; qt < 4; ++qt) {
    #pragma unroll
    for (int mt = 0; mt < 2; ++mt)
      *(float4*)&mrg[((size_t)w * 64 + qt * 16 + l15) * 36 + mt * 16 + quad * 4] =
          make_float4(accO[qt][mt][0], accO[qt][mt][1], accO[qt][mt][2], accO[qt][mt][3]);
    if (lane < 16) sS[w * 64 + qt * 16 + l15] = spart[qt];
  }
  __syncthreads();

  // reduce over waves + normalize (thread -> q = t>>2, 8 channels)
  int rq = t >> 2, rc = (t & 3) * 8;
  float yv[8];
  {
    float ssum = sS[rq] + sS[64 + rq] + sS[128 + rq] + sS[192 + rq];
    float inv = 1.0f / ssum;
    #pragma unroll
    for (int h = 0; h < 2; ++h) {
      float4 a = *(const float4*)&mrg[(size_t)rq * 36 + rc + 4 * h];
      float4 b = *(const float4*)&mrg[(size_t)(64 + rq) * 36 + rc + 4 * h];
      float4 c = *(const float4*)&mrg[(size_t)(128 + rq) * 36 + rc + 4 * h];
      float4 d = *(const float4*)&mrg[(size_t)(192 + rq) * 36 + rc + 4 * h];
      yv[4*h+0] = (a.x + b.x + c.x + d.x) * inv;
      yv[4*h+1] = (a.y + b.y + c.y + d.y) * inv;
      yv[4*h+2] = (a.z + b.z + c.z + d.z) * inv;
      yv[4*h+3] = (a.w + b.w + c.w + d.w) * inv;
    }
  }
  __syncthreads();

  // write y bf16 hi/lo planes into reused mrg space (cvt_pk pairs)
  ushort* yH = (ushort*)mrg;                 // [q][YS]
  ushort* yL = yH + 64 * YS;
  {
    union { uint u[4]; uint4 v; } Hh, Ll;
    #pragma unroll
    for (int jj = 0; jj < 4; ++jj)
      split2(yv[2 * jj], yv[2 * jj + 1], Hh.u[jj], Ll.u[jj]);
    *(uint4*)&yH[rq * YS + rc] = Hh.v;
    *(uint4*)&yL[rq * YS + rc] = Ll.v;
  }
  __syncthreads();

  // epilogue: wave w -> cout tile [w*16, w*16+16); z = W.y + bW + x
  sfrag ah[2], al[2];
  #pragma unroll
  for (int kt = 0; kt < 2; ++kt) {
    ah[kt] = *(const sfrag*)(WWH + ((size_t)(w * 2 + kt) * 64 + lane) * 4);
    al[kt] = *(const sfrag*)(WWL + ((size_t)(w * 2 + kt) * 64 + lane) * 4);
  }
  #pragma unroll
  for (int nt = 0; nt < 4; ++nt) {
    f32x4 d = (f32x4){0.f,0.f,0.f,0.f};
    #pragma unroll
    for (int kt = 0; kt < 2; ++kt) {
      sfrag yhf = *(const sfrag*)&yH[(nt * 16 + l15) * YS + kt * 16 + quad * 4];
      sfrag ylf = *(const sfrag*)&yL[(nt * 16 + l15) * YS + kt * 16 + quad * 4];
      d = __builtin_amdgcn_mfma_f32_16x16x16bf16_1k(ah[kt], yhf, d, 0, 0, 0);
      d = __builtin_amdgcn_mfma_f32_16x16x16bf16_1k(al[kt], yhf, d, 0, 0, 0);
      d = __builtin_amdgcn_mfma_f32_16x16x16bf16_1k(ah[kt], ylf, d, 0, 0, 0);
    }
    #pragma unroll
    for (int r = 0; r < 4; ++r) {
      int cout = w * 16 + quad * 4 + r;
      size_t zi = ((size_t)bb << 18) + ((size_t)cout << 12)
                + (size_t)(bq * 4 + nt) * 16 + l15;
      z[zi] = d[r] + bW[cout] + x[zi];
    }
  }
}

extern "C" void kernel_launch(void* const* d_in, const int* in_sizes, int n_in,
                              void* d_out, int out_size, void* d_ws, size_t ws_size,
                              hipStream_t stream) {
  const float* x   = (const float*)d_in[0];
  const float* w_o = (const float*)d_in[1];
  const float* b_o = (const float*)d_in[2];
  const float* w_t = (const float*)d_in[3];
  const float* b_t = (const float*)d_in[4];
  const float* w_p = (const float*)d_in[5];
  const float* b_p = (const float*)d_in[6];
  const float* w_W = (const float*)d_in[7];
  const float* b_W = (const float*)d_in[8];
  float* z = (float*)d_out;

  ushort* QH = (ushort*)d_ws;                         // 16*256*64*8 = 2097152
  ushort* QL = QH + 2097152;
  ushort* KH = QL + 2097152;                          // 16*64*64*8 = 524288
  ushort* KL = KH + 524288;
  ushort* VF = KL + 524288;                           // 16*64*2*64*4 = 524288
  ushort* WTH = VF + 524288;                          // 4*64*8 = 2048 each
  ushort* WTL = WTH + 2048;
  ushort* WPH = WTL + 2048;
  ushort* WPL = WPH + 2048;
  ushort* WOH = WPL + 2048;
  ushort* WWH = WOH + 2048;                           // 8*64*4 = 2048 each
  ushort* WWL = WWH + 2048;

  k_prep<<<dim3(1), dim3(256), 0, stream>>>(
      w_t, w_p, w_o, w_W, WTH, WTL, WPH, WPL, WOH, WWH, WWL);
  k_qkv<<<dim3(B_SZ * 32), dim3(512), 0, stream>>>(
      x, WTH, WTL, b_t, WPH, WPL, b_p, WOH, b_o, QH, QL, KH, KL, VF);
  k_attn<<<dim3(B_SZ * 64), dim3(256), 0, stream>>>(
      QH, QL, KH, KL, VF, x, WWH, WWL, b_W, z);
}